// Round 3
// baseline (411.005 us; speedup 1.0000x reference)
//
#include <hip/hip_runtime.h>

#define DIN  128
#define DOUT 64
#define GR   128    // rows per gemm block (8 waves x 16 rows)
#define BW   512    // nodes per bucket (power of 2)
#define BSH  9      // log2(BW)
#define EPC  4096   // edges per chunk
#define NSTATB 400  // stat partial blocks

// ---------- K1: per-chunk, per-bucket histograms for BOTH directions ----------
__global__ __launch_bounds__(256) void k_countboth(const int* __restrict__ src,
                                                   const int* __restrict__ dst,
                                                   unsigned* __restrict__ counts,
                                                   int NBUK, int NC, int E) {
    __shared__ int h0[256], h1[256];
    for (int j = threadIdx.x; j < NBUK; j += 256) { h0[j] = 0; h1[j] = 0; }
    __syncthreads();
    int start = blockIdx.x * EPC;
    int end = min(start + EPC, E);
    for (int i = start + threadIdx.x; i < end; i += 256) {
        atomicAdd(&h0[dst[i] >> BSH], 1);
        atomicAdd(&h1[src[i] >> BSH], 1);
    }
    __syncthreads();
    int M = NBUK * NC;
    for (int j = threadIdx.x; j < NBUK; j += 256) {
        counts[j * NC + blockIdx.x]     = (unsigned)h0[j];
        counts[M + j * NC + blockIdx.x] = (unsigned)h1[j];
    }
}

// ---------- generic 3-kernel exclusive scan ----------
__global__ __launch_bounds__(256) void k_scanA(const unsigned* __restrict__ data,
                                               unsigned* __restrict__ bsums, int n) {
    __shared__ unsigned s[256];
    int i = blockIdx.x * 256 + threadIdx.x;
    s[threadIdx.x] = (i < n) ? data[i] : 0u;
    __syncthreads();
    for (int st = 128; st > 0; st >>= 1) {
        if (threadIdx.x < st) s[threadIdx.x] += s[threadIdx.x + st];
        __syncthreads();
    }
    if (threadIdx.x == 0) bsums[blockIdx.x] = s[0];
}

__global__ __launch_bounds__(1024) void k_scan2(unsigned* __restrict__ bsums, int NB) {
    __shared__ unsigned s[1024];
    int tid = threadIdx.x;
    unsigned v = (tid < NB) ? bsums[tid] : 0u;
    s[tid] = v;
    __syncthreads();
    for (int st = 1; st < 1024; st <<= 1) {
        unsigned t = (tid >= st) ? s[tid - st] : 0u;
        __syncthreads();
        s[tid] += t;
        __syncthreads();
    }
    if (tid < NB) bsums[tid] = s[tid] - v;   // exclusive
}

__global__ __launch_bounds__(256) void k_scanC(unsigned* __restrict__ data,
                                               const unsigned* __restrict__ bsums, int n) {
    __shared__ unsigned s[256];
    int i = blockIdx.x * 256 + threadIdx.x;
    unsigned v = (i < n) ? data[i] : 0u;
    s[threadIdx.x] = v;
    __syncthreads();
    for (int st = 1; st < 256; st <<= 1) {
        unsigned t = (threadIdx.x >= st) ? s[threadIdx.x - st] : 0u;
        __syncthreads();
        s[threadIdx.x] += t;
        __syncthreads();
    }
    if (i < n) data[i] = s[threadIdx.x] - v + bsums[blockIdx.x];
}

// ---------- K5: bucket-major reorder (coalesced block-private segments) ----------
__global__ __launch_bounds__(256) void k_bucket(const int* __restrict__ key,
                                                const int* __restrict__ other,
                                                const unsigned* __restrict__ counts,
                                                int dirOff, unsigned dirBase,
                                                int2* __restrict__ bucketed,
                                                int NBUK, int NC, int E) {
    __shared__ int cur[256];
    for (int j = threadIdx.x; j < NBUK; j += 256)
        cur[j] = (int)(counts[dirOff + j * NC + blockIdx.x] - dirBase);
    __syncthreads();
    int start = blockIdx.x * EPC;
    int end = min(start + EPC, E);
    for (int i = start + threadIdx.x; i < end; i += 256) {
        int k = key[i], o = other[i];
        int pos = atomicAdd(&cur[k >> BSH], 1);
        bucketed[pos] = make_int2(k, o);
    }
}

// ---------- K6: per-bucket CSR finalize — degrees, offsets, private scatter ----------
__global__ __launch_bounds__(256) void k_csr(const int2* __restrict__ bucketed,
                                             const unsigned* __restrict__ counts,
                                             unsigned* __restrict__ off,
                                             int* __restrict__ pay,
                                             unsigned* __restrict__ cnt,
                                             float* __restrict__ dinv,
                                             int dirOff, unsigned dirBase,
                                             int NBUK, int NC, int N, int E) {
    __shared__ int sH[BW];
    __shared__ int sS[2][BW];
    __shared__ int sC[BW];
    int b = blockIdx.x;
    int base = (int)(counts[dirOff + b * NC] - dirBase);
    int end  = (b + 1 < NBUK) ? (int)(counts[dirOff + (b + 1) * NC] - dirBase) : E;

    for (int j = threadIdx.x; j < BW; j += 256) sH[j] = 0;
    __syncthreads();
    for (int i = base + threadIdx.x; i < end; i += 256)
        atomicAdd(&sH[bucketed[i].x & (BW - 1)], 1);
    __syncthreads();
    for (int j = threadIdx.x; j < BW; j += 256) sS[0][j] = sH[j];
    __syncthreads();
    int pin = 0;
    for (int st = 1; st < BW; st <<= 1) {
        for (int j = threadIdx.x; j < BW; j += 256) {
            int v = sS[pin][j];
            if (j >= st) v += sS[pin][j - st];
            sS[pin ^ 1][j] = v;
        }
        __syncthreads();
        pin ^= 1;
    }
    int lo = b * BW;
    for (int j = threadIdx.x; j < BW; j += 256) {
        int excl = j ? sS[pin][j - 1] : 0;
        sC[j] = excl;
        int n = lo + j;
        if (n < N) {
            off[n] = (unsigned)(base + excl);
            if (cnt) {
                cnt[n] = (unsigned)sH[j];
                dinv[n] = rsqrtf((float)sH[j] + 1.f);
            }
        }
    }
    if (threadIdx.x == 0 && b == NBUK - 1) off[N] = (unsigned)E;
    __syncthreads();
    for (int i = base + threadIdx.x; i < end; i += 256) {
        int2 p = bucketed[i];
        int pos = base + atomicAdd(&sC[p.x & (BW - 1)], 1);
        pay[pos] = p.y;
    }
}

// ---------- K7: h0s = dinv[n] * (x[n] @ W) ----------
// Zero-LDS design: lane = output column (DOUT=64 = wave width), wave = 16 rows.
// x loads are wave-uniform -> scalar pipe (s_load_dwordx4) via readfirstlane;
// W streams per-lane coalesced from vL1 (32 KB = whole W resident).
// FMA = v_fmac_f32 vacc, s_x, v_w. No LDS, no syncthreads, occupancy
// wave-limited instead of LDS-limited.
__global__ __launch_bounds__(512) void k_gemm(const float* __restrict__ x,
                                              const float* __restrict__ W,
                                              const float* __restrict__ dinv,
                                              float* __restrict__ h0s, int N) {
    int t = threadIdx.x;
    int c = t & 63;                                         // output column
    int wv = __builtin_amdgcn_readfirstlane(t >> 6);        // wave 0..7 (uniform)
    int base = blockIdx.x * GR + wv * 16;                   // first row of wave
    if (base >= N) return;
    const float* xw = x + (size_t)base * DIN;

    float acc[16] = {};
    if (base + 16 <= N) {
        for (int k = 0; k < DIN; k += 4) {
            float w0 = W[(k + 0) * DOUT + c];
            float w1 = W[(k + 1) * DOUT + c];
            float w2 = W[(k + 2) * DOUT + c];
            float w3 = W[(k + 3) * DOUT + c];
#pragma unroll
            for (int i = 0; i < 16; ++i) {
                float4 a = *(const float4*)(xw + (size_t)i * DIN + k);  // uniform -> s_load
                acc[i] = fmaf(a.x, w0, fmaf(a.y, w1, fmaf(a.z, w2, fmaf(a.w, w3, acc[i]))));
            }
        }
#pragma unroll
        for (int i = 0; i < 16; ++i) {
            int n = base + i;
            h0s[(size_t)n * DOUT + c] = acc[i] * dinv[n];
        }
    } else {
        // tail block: per-row uniform guard
        for (int k = 0; k < DIN; k += 4) {
            float w0 = W[(k + 0) * DOUT + c];
            float w1 = W[(k + 1) * DOUT + c];
            float w2 = W[(k + 2) * DOUT + c];
            float w3 = W[(k + 3) * DOUT + c];
#pragma unroll
            for (int i = 0; i < 16; ++i) {
                if (base + i < N) {
                    float4 a = *(const float4*)(xw + (size_t)i * DIN + k);
                    acc[i] = fmaf(a.x, w0, fmaf(a.y, w1, fmaf(a.z, w2, fmaf(a.w, w3, acc[i]))));
                }
            }
        }
#pragma unroll
        for (int i = 0; i < 16; ++i) {
            int n = base + i;
            if (n < N) h0s[(size_t)n * DOUT + c] = acc[i] * dinv[n];
        }
    }
}

// ---------- K8: gather agg + fused combine ----------
// One node per 16-lane GROUP (4 nodes/wave, 16/block). A row is exactly
// 16 lanes x float4 = 256B. Lane q preloads pay[beg+q] (covers deg<=16 in
// ONE coalesced load); edge ids then come from __shfl registers, removing
// the pay load from the dependent chain. 4 independent chains per wave.
__global__ __launch_bounds__(256) void k_agg(const unsigned* __restrict__ off,
                                             const int* __restrict__ pay,
                                             const float* __restrict__ dinv,
                                             const float* __restrict__ h0s,
                                             const float* __restrict__ b,
                                             float* __restrict__ h, int N) {
    int t = threadIdx.x;
    int grp = t >> 4;          // 0..15
    int q = t & 15;
    int n = blockIdx.x * 16 + grp;
    if (n >= N) return;
    unsigned beg = off[n], end = off[n + 1];
    float4 acc = make_float4(0.f, 0.f, 0.f, 0.f);
    for (unsigned base2 = beg; base2 < end; base2 += 16) {
        unsigned idx = base2 + q;
        int pd = (idx < end) ? pay[idx] : 0;
        int jmax = (int)min(16u, end - base2);
        int j = 0;
        for (; j + 4 <= jmax; j += 4) {
            int s0 = __shfl(pd, j + 0, 16);
            int s1 = __shfl(pd, j + 1, 16);
            int s2 = __shfl(pd, j + 2, 16);
            int s3 = __shfl(pd, j + 3, 16);
            float4 a0 = *(const float4*)(h0s + (size_t)s0 * DOUT + 4 * q);
            float4 a1 = *(const float4*)(h0s + (size_t)s1 * DOUT + 4 * q);
            float4 a2 = *(const float4*)(h0s + (size_t)s2 * DOUT + 4 * q);
            float4 a3 = *(const float4*)(h0s + (size_t)s3 * DOUT + 4 * q);
            acc.x += (a0.x + a1.x) + (a2.x + a3.x);
            acc.y += (a0.y + a1.y) + (a2.y + a3.y);
            acc.z += (a0.z + a1.z) + (a2.z + a3.z);
            acc.w += (a0.w + a1.w) + (a2.w + a3.w);
        }
        for (; j < jmax; ++j) {
            int s = __shfl(pd, j, 16);
            float4 a = *(const float4*)(h0s + (size_t)s * DOUT + 4 * q);
            acc.x += a.x; acc.y += a.y; acc.z += a.z; acc.w += a.w;
        }
    }
    float dv = dinv[n];
    float4 hs = *(const float4*)(h0s + (size_t)n * DOUT + 4 * q);
    float4 bv = *(const float4*)(b + 4 * q);
    float4 o;
    o.x = dv * (acc.x + hs.x) + bv.x;
    o.y = dv * (acc.y + hs.y) + bv.y;
    o.z = dv * (acc.z + hs.z) + bv.z;
    o.w = dv * (acc.w + hs.w) + bv.w;
    *(float4*)(h + (size_t)n * DOUT + 4 * q) = o;
}

// ---------- K9: gather energy + S (same group-per-node structure) ----------
__global__ __launch_bounds__(256) void k_energy(const unsigned* __restrict__ off,
                                                const int* __restrict__ pay,
                                                const float* __restrict__ h,
                                                float* __restrict__ e,
                                                float* __restrict__ S, int N) {
    int t = threadIdx.x;
    int grp = t >> 4;
    int q = t & 15;
    int n = blockIdx.x * 16 + grp;
    if (n >= N) return;
    unsigned beg = off[n], end = off[n + 1];
    float4 hm = *(const float4*)(h + (size_t)n * DOUT + 4 * q);
    float4 Sa = make_float4(0.f, 0.f, 0.f, 0.f);
    float esum = 0.f;
    for (unsigned base2 = beg; base2 < end; base2 += 16) {
        unsigned idx = base2 + q;
        int pd = (idx < end) ? pay[idx] : 0;
        int jmax = (int)min(16u, end - base2);
        int j = 0;
        for (; j + 4 <= jmax; j += 4) {
            int s0 = __shfl(pd, j + 0, 16);
            int s1 = __shfl(pd, j + 1, 16);
            int s2 = __shfl(pd, j + 2, 16);
            int s3 = __shfl(pd, j + 3, 16);
            float4 a0 = *(const float4*)(h + (size_t)s0 * DOUT + 4 * q);
            float4 a1 = *(const float4*)(h + (size_t)s1 * DOUT + 4 * q);
            float4 a2 = *(const float4*)(h + (size_t)s2 * DOUT + 4 * q);
            float4 a3 = *(const float4*)(h + (size_t)s3 * DOUT + 4 * q);
            Sa.x += (a0.x + a1.x) + (a2.x + a3.x);
            Sa.y += (a0.y + a1.y) + (a2.y + a3.y);
            Sa.z += (a0.z + a1.z) + (a2.z + a3.z);
            Sa.w += (a0.w + a1.w) + (a2.w + a3.w);
            float dx, dy, dz, dw;
            dx = hm.x - a0.x; dy = hm.y - a0.y; dz = hm.z - a0.z; dw = hm.w - a0.w;
            esum += dx * dx + dy * dy + dz * dz + dw * dw;
            dx = hm.x - a1.x; dy = hm.y - a1.y; dz = hm.z - a1.z; dw = hm.w - a1.w;
            esum += dx * dx + dy * dy + dz * dz + dw * dw;
            dx = hm.x - a2.x; dy = hm.y - a2.y; dz = hm.z - a2.z; dw = hm.w - a2.w;
            esum += dx * dx + dy * dy + dz * dz + dw * dw;
            dx = hm.x - a3.x; dy = hm.y - a3.y; dz = hm.z - a3.z; dw = hm.w - a3.w;
            esum += dx * dx + dy * dy + dz * dz + dw * dw;
        }
        for (; j < jmax; ++j) {
            int s = __shfl(pd, j, 16);
            float4 a = *(const float4*)(h + (size_t)s * DOUT + 4 * q);
            Sa.x += a.x; Sa.y += a.y; Sa.z += a.z; Sa.w += a.w;
            float dx = hm.x - a.x, dy = hm.y - a.y, dz = hm.z - a.z, dw = hm.w - a.w;
            esum += dx * dx + dy * dy + dz * dz + dw * dw;
        }
    }
#pragma unroll
    for (int m = 1; m <= 8; m <<= 1) esum += __shfl_xor(esum, m, 16);
    if (q == 0) e[n] = esum;
    *(float4*)(S + (size_t)n * DOUT + 4 * q) = Sa;
}

// ---------- K10: per-block softmax partials (m, Z, M) ----------
__global__ __launch_bounds__(256) void k_stats1(const float* __restrict__ e,
                                                const float* __restrict__ Tptr,
                                                float* __restrict__ part, int N) {
    float T = *Tptr;
    float m = -3.4e38f;
    int i0 = blockIdx.x * 256 + threadIdx.x;
    int stride = gridDim.x * 256;
    for (int i = i0; i < N; i += stride) m = fmaxf(m, -e[i] / T);
    __shared__ float sm[256];
    sm[threadIdx.x] = m;
    __syncthreads();
    for (int s = 128; s > 0; s >>= 1) {
        if (threadIdx.x < s) sm[threadIdx.x] = fmaxf(sm[threadIdx.x], sm[threadIdx.x + s]);
        __syncthreads();
    }
    float bm = sm[0];
    __syncthreads();
    float z = 0.f, mm = 0.f;
    for (int i = i0; i < N; i += stride) {
        float t = -e[i] / T - bm;
        float w = __expf(t);
        z += w;
        mm += w * t;
    }
    __shared__ float sz[256], sM[256];
    sz[threadIdx.x] = z;
    sM[threadIdx.x] = mm;
    __syncthreads();
    for (int s = 128; s > 0; s >>= 1) {
        if (threadIdx.x < s) {
            sz[threadIdx.x] += sz[threadIdx.x + s];
            sM[threadIdx.x] += sM[threadIdx.x + s];
        }
        __syncthreads();
    }
    if (threadIdx.x == 0) {
        part[blockIdx.x * 3 + 0] = bm;
        part[blockIdx.x * 3 + 1] = sz[0];
        part[blockIdx.x * 3 + 2] = sM[0];
    }
}

// ---------- K11: merge partials -> st = {m, Z, M} ----------
__global__ __launch_bounds__(256) void k_stats2(const float* __restrict__ part,
                                                float* __restrict__ st, int P) {
    __shared__ float sm[256];
    float m = -3.4e38f;
    for (int i = threadIdx.x; i < P; i += 256) m = fmaxf(m, part[3 * i]);
    sm[threadIdx.x] = m;
    __syncthreads();
    for (int s = 128; s > 0; s >>= 1) {
        if (threadIdx.x < s) sm[threadIdx.x] = fmaxf(sm[threadIdx.x], sm[threadIdx.x + s]);
        __syncthreads();
    }
    float gm = sm[0];
    __syncthreads();
    float Z = 0.f, M = 0.f;
    for (int i = threadIdx.x; i < P; i += 256) {
        float mb = part[3 * i], zb = part[3 * i + 1], Mb = part[3 * i + 2];
        float d = mb - gm, eb = __expf(d);
        Z += eb * zb;
        M += eb * (Mb + d * zb);
    }
    __shared__ float sz[256], sM2[256];
    sz[threadIdx.x] = Z;
    sM2[threadIdx.x] = M;
    __syncthreads();
    for (int s = 128; s > 0; s >>= 1) {
        if (threadIdx.x < s) {
            sz[threadIdx.x] += sz[threadIdx.x + s];
            sM2[threadIdx.x] += sM2[threadIdx.x + s];
        }
        __syncthreads();
    }
    if (threadIdx.x == 0) {
        st[0] = gm;
        st[1] = sz[0];
        st[2] = sM2[0];
    }
}

// ---------- K12: c_n = p_n * (logp_n + H) ----------
__global__ __launch_bounds__(256) void k_coef(const float* __restrict__ e,
                                              const float* __restrict__ Tptr,
                                              const float* __restrict__ st,
                                              float* __restrict__ c, int N) {
    int n = blockIdx.x * 256 + threadIdx.x;
    if (n >= N) return;
    float T = *Tptr;
    float gm = st[0], Z = st[1], M = st[2];
    float logZ = logf(Z);
    float H = logZ - M / Z;
    float t = -e[n] / T - gm;
    float lp = t - logZ;
    c[n] = expf(lp) * (lp + H);
}

// ---------- K13: out-CSR gather of A,B + fused final ----------
// group-per-node: c[pay] pre-gathered alongside pay, both shfl-broadcast.
// A replicates across the group; B accumulates each lane's float4 slice.
// No cross-group reduction needed at all.
__global__ __launch_bounds__(256) void k_grad_final(const unsigned* __restrict__ off,
                                                    const int* __restrict__ pay,
                                                    const float* __restrict__ c,
                                                    const float* __restrict__ h,
                                                    const float* __restrict__ S,
                                                    const unsigned* __restrict__ cnt,
                                                    const float* __restrict__ wptr,
                                                    float* __restrict__ out, int N) {
    int t = threadIdx.x;
    int grp = t >> 4;
    int q = t & 15;
    int n = blockIdx.x * 16 + grp;
    if (n >= N) return;
    unsigned beg = off[n], end = off[n + 1];
    float A = 0.f;
    float4 B = make_float4(0.f, 0.f, 0.f, 0.f);
    for (unsigned base2 = beg; base2 < end; base2 += 16) {
        unsigned idx = base2 + q;
        int pd = 0;
        float cv = 0.f;
        if (idx < end) {
            pd = pay[idx];
            cv = c[pd];
        }
        int jmax = (int)min(16u, end - base2);
        int j = 0;
        for (; j + 4 <= jmax; j += 4) {
            int s0 = __shfl(pd, j + 0, 16);
            int s1 = __shfl(pd, j + 1, 16);
            int s2 = __shfl(pd, j + 2, 16);
            int s3 = __shfl(pd, j + 3, 16);
            float c0 = __shfl(cv, j + 0, 16);
            float c1 = __shfl(cv, j + 1, 16);
            float c2 = __shfl(cv, j + 2, 16);
            float c3 = __shfl(cv, j + 3, 16);
            float4 a0 = *(const float4*)(h + (size_t)s0 * DOUT + 4 * q);
            float4 a1 = *(const float4*)(h + (size_t)s1 * DOUT + 4 * q);
            float4 a2 = *(const float4*)(h + (size_t)s2 * DOUT + 4 * q);
            float4 a3 = *(const float4*)(h + (size_t)s3 * DOUT + 4 * q);
            A += (c0 + c1) + (c2 + c3);
            B.x = fmaf(c0, a0.x, fmaf(c1, a1.x, fmaf(c2, a2.x, fmaf(c3, a3.x, B.x))));
            B.y = fmaf(c0, a0.y, fmaf(c1, a1.y, fmaf(c2, a2.y, fmaf(c3, a3.y, B.y))));
            B.z = fmaf(c0, a0.z, fmaf(c1, a1.z, fmaf(c2, a2.z, fmaf(c3, a3.z, B.z))));
            B.w = fmaf(c0, a0.w, fmaf(c1, a1.w, fmaf(c2, a2.w, fmaf(c3, a3.w, B.w))));
        }
        for (; j < jmax; ++j) {
            int s = __shfl(pd, j, 16);
            float cj = __shfl(cv, j, 16);
            float4 a = *(const float4*)(h + (size_t)s * DOUT + 4 * q);
            A += cj;
            B.x = fmaf(cj, a.x, B.x);
            B.y = fmaf(cj, a.y, B.y);
            B.z = fmaf(cj, a.z, B.z);
            B.w = fmaf(cj, a.w, B.w);
        }
    }
    size_t idx4 = (size_t)n * DOUT + 4 * q;
    float4 hm = *(const float4*)(h + idx4);
    float4 Sv = *(const float4*)(S + idx4);
    float cn = c[n];
    float cc = (float)cnt[n];
    float w = *wptr;
    float4 o;
    o.x = hm.x + w * (2.f * cn * (cc * hm.x - Sv.x) + 2.f * (A * hm.x - B.x));
    o.y = hm.y + w * (2.f * cn * (cc * hm.y - Sv.y) + 2.f * (A * hm.y - B.y));
    o.z = hm.z + w * (2.f * cn * (cc * hm.z - Sv.z) + 2.f * (A * hm.z - B.z));
    o.w = hm.w + w * (2.f * cn * (cc * hm.w - Sv.w) + 2.f * (A * hm.w - B.w));
    *(float4*)(out + idx4) = o;
}

extern "C" void kernel_launch(void* const* d_in, const int* in_sizes, int n_in,
                              void* d_out, int out_size, void* d_ws, size_t ws_size,
                              hipStream_t stream) {
    const float* x    = (const float*)d_in[0];
    const int*   ei   = (const int*)d_in[1];
    const float* wptr = (const float*)d_in[2];
    const float* Tptr = (const float*)d_in[3];
    const float* W    = (const float*)d_in[4];
    const float* b    = (const float*)d_in[5];
    float* out = (float*)d_out;

    const int N  = in_sizes[0] / DIN;   // 100000
    const int E  = in_sizes[1] / 2;     // 1000000
    const int NE = N * DOUT;
    const int* src = ei;
    const int* dst = ei + E;

    const int NBUK = (N + BW - 1) / BW;         // 196
    const int NC   = (E + EPC - 1) / EPC;       // 245
    const int M    = NBUK * NC;
    const int M2   = 2 * M;
    const int NBs  = (M2 + 255) / 256;          // <= 1024

    // workspace layout
    float*    h0s  = (float*)d_ws;                    // NE (reused as S later)
    float*    h    = h0s + NE;                        // NE
    int2*     bkt  = (int2*)(h + NE);                 // E int2 (8 MB, reused per dir)
    int*      pay1 = (int*)(bkt + E);                 // E (in-CSR payload: src ids)
    int*      pay2 = pay1 + E;                        // E (out-CSR payload: dst ids)
    unsigned* counts = (unsigned*)(pay2 + E);         // 2*M
    unsigned* bsum = counts + M2;                     // <=1024
    unsigned* off1 = bsum + 1024;                     // N+1
    unsigned* off2 = off1 + N + 1;                    // N+1
    unsigned* cnt  = off2 + N + 1;                    // N
    float*    e    = (float*)(cnt + N);               // N
    float*    c    = e + N;                           // N
    float*    dinv = c + N;                           // N
    float*    part = dinv + N;                        // 3*NSTATB
    float*    st   = part + 3 * NSTATB;               // 3
    float*    S    = h0s;                             // reuse after k_agg

    const int nodeG = (N + 15) / 16;    // 16 nodes per 256-thread block
    const int nodeBlocks = (N + 255) / 256;

    // build both direction counts + one combined scan
    k_countboth<<<NC, 256, 0, stream>>>(src, dst, counts, NBUK, NC, E);
    k_scanA<<<NBs, 256, 0, stream>>>(counts, bsum, M2);
    k_scan2<<<1, 1024, 0, stream>>>(bsum, NBs);
    k_scanC<<<NBs, 256, 0, stream>>>(counts, bsum, M2);

    // direction 0: in-CSR (key=dst, payload=src) -> off1/pay1 + cnt/dinv
    k_bucket<<<NC, 256, 0, stream>>>(dst, src, counts, 0, 0u, bkt, NBUK, NC, E);
    k_csr<<<NBUK, 256, 0, stream>>>(bkt, counts, off1, pay1, cnt, dinv,
                                    0, 0u, NBUK, NC, N, E);
    // direction 1: out-CSR (key=src, payload=dst) -> off2/pay2
    k_bucket<<<NC, 256, 0, stream>>>(src, dst, counts, M, (unsigned)E, bkt, NBUK, NC, E);
    k_csr<<<NBUK, 256, 0, stream>>>(bkt, counts, off2, pay2, nullptr, nullptr,
                                    M, (unsigned)E, NBUK, NC, N, E);

    k_gemm<<<(N + GR - 1) / GR, 512, 0, stream>>>(x, W, dinv, h0s, N);
    k_agg<<<nodeG, 256, 0, stream>>>(off1, pay1, dinv, h0s, b, h, N);
    k_energy<<<nodeG, 256, 0, stream>>>(off1, pay1, h, e, S, N);
    k_stats1<<<NSTATB, 256, 0, stream>>>(e, Tptr, part, N);
    k_stats2<<<1, 256, 0, stream>>>(part, st, NSTATB);
    k_coef<<<nodeBlocks, 256, 0, stream>>>(e, Tptr, st, c, N);
    k_grad_final<<<nodeG, 256, 0, stream>>>(off2, pay2, c, h, S, cnt, wptr, out, N);
}

// Round 4
// 333.833 us; speedup vs baseline: 1.2312x; 1.2312x over previous
//
#include <hip/hip_runtime.h>

#define DIN  128
#define DOUT 64
#define GTN  128    // rows per gemm block (256 thr = 16 cols-of-4 x 16 row-groups-of-8)
#define BW   512    // nodes per bucket (power of 2)
#define BSH  9      // log2(BW)
#define EPC  4096   // edges per chunk
#define NSTATB 400  // stat partial blocks

// ---------- K1: per-chunk, per-bucket histograms for BOTH directions ----------
__global__ __launch_bounds__(256) void k_countboth(const int* __restrict__ src,
                                                   const int* __restrict__ dst,
                                                   unsigned* __restrict__ counts,
                                                   int NBUK, int NC, int E) {
    __shared__ int h0[256], h1[256];
    for (int j = threadIdx.x; j < NBUK; j += 256) { h0[j] = 0; h1[j] = 0; }
    __syncthreads();
    int start = blockIdx.x * EPC;
    int end = min(start + EPC, E);
    for (int i = start + threadIdx.x; i < end; i += 256) {
        atomicAdd(&h0[dst[i] >> BSH], 1);
        atomicAdd(&h1[src[i] >> BSH], 1);
    }
    __syncthreads();
    int M = NBUK * NC;
    for (int j = threadIdx.x; j < NBUK; j += 256) {
        counts[j * NC + blockIdx.x]     = (unsigned)h0[j];
        counts[M + j * NC + blockIdx.x] = (unsigned)h1[j];
    }
}

// ---------- generic 3-kernel exclusive scan ----------
__global__ __launch_bounds__(256) void k_scanA(const unsigned* __restrict__ data,
                                               unsigned* __restrict__ bsums, int n) {
    __shared__ unsigned s[256];
    int i = blockIdx.x * 256 + threadIdx.x;
    s[threadIdx.x] = (i < n) ? data[i] : 0u;
    __syncthreads();
    for (int st = 128; st > 0; st >>= 1) {
        if (threadIdx.x < st) s[threadIdx.x] += s[threadIdx.x + st];
        __syncthreads();
    }
    if (threadIdx.x == 0) bsums[blockIdx.x] = s[0];
}

__global__ __launch_bounds__(1024) void k_scan2(unsigned* __restrict__ bsums, int NB) {
    __shared__ unsigned s[1024];
    int tid = threadIdx.x;
    unsigned v = (tid < NB) ? bsums[tid] : 0u;
    s[tid] = v;
    __syncthreads();
    for (int st = 1; st < 1024; st <<= 1) {
        unsigned t = (tid >= st) ? s[tid - st] : 0u;
        __syncthreads();
        s[tid] += t;
        __syncthreads();
    }
    if (tid < NB) bsums[tid] = s[tid] - v;   // exclusive
}

__global__ __launch_bounds__(256) void k_scanC(unsigned* __restrict__ data,
                                               const unsigned* __restrict__ bsums, int n) {
    __shared__ unsigned s[256];
    int i = blockIdx.x * 256 + threadIdx.x;
    unsigned v = (i < n) ? data[i] : 0u;
    s[threadIdx.x] = v;
    __syncthreads();
    for (int st = 1; st < 256; st <<= 1) {
        unsigned t = (threadIdx.x >= st) ? s[threadIdx.x - st] : 0u;
        __syncthreads();
        s[threadIdx.x] += t;
        __syncthreads();
    }
    if (i < n) data[i] = s[threadIdx.x] - v + bsums[blockIdx.x];
}

// ---------- K5: bucket-major reorder (coalesced block-private segments) ----------
__global__ __launch_bounds__(256) void k_bucket(const int* __restrict__ key,
                                                const int* __restrict__ other,
                                                const unsigned* __restrict__ counts,
                                                int dirOff, unsigned dirBase,
                                                int2* __restrict__ bucketed,
                                                int NBUK, int NC, int E) {
    __shared__ int cur[256];
    for (int j = threadIdx.x; j < NBUK; j += 256)
        cur[j] = (int)(counts[dirOff + j * NC + blockIdx.x] - dirBase);
    __syncthreads();
    int start = blockIdx.x * EPC;
    int end = min(start + EPC, E);
    for (int i = start + threadIdx.x; i < end; i += 256) {
        int k = key[i], o = other[i];
        int pos = atomicAdd(&cur[k >> BSH], 1);
        bucketed[pos] = make_int2(k, o);
    }
}

// ---------- K6: per-bucket CSR finalize — degrees, offsets, private scatter ----------
__global__ __launch_bounds__(256) void k_csr(const int2* __restrict__ bucketed,
                                             const unsigned* __restrict__ counts,
                                             unsigned* __restrict__ off,
                                             int* __restrict__ pay,
                                             unsigned* __restrict__ cnt,
                                             float* __restrict__ dinv,
                                             int dirOff, unsigned dirBase,
                                             int NBUK, int NC, int N, int E) {
    __shared__ int sH[BW];
    __shared__ int sS[2][BW];
    __shared__ int sC[BW];
    int b = blockIdx.x;
    int base = (int)(counts[dirOff + b * NC] - dirBase);
    int end  = (b + 1 < NBUK) ? (int)(counts[dirOff + (b + 1) * NC] - dirBase) : E;

    for (int j = threadIdx.x; j < BW; j += 256) sH[j] = 0;
    __syncthreads();
    for (int i = base + threadIdx.x; i < end; i += 256)
        atomicAdd(&sH[bucketed[i].x & (BW - 1)], 1);
    __syncthreads();
    for (int j = threadIdx.x; j < BW; j += 256) sS[0][j] = sH[j];
    __syncthreads();
    int pin = 0;
    for (int st = 1; st < BW; st <<= 1) {
        for (int j = threadIdx.x; j < BW; j += 256) {
            int v = sS[pin][j];
            if (j >= st) v += sS[pin][j - st];
            sS[pin ^ 1][j] = v;
        }
        __syncthreads();
        pin ^= 1;
    }
    int lo = b * BW;
    for (int j = threadIdx.x; j < BW; j += 256) {
        int excl = j ? sS[pin][j - 1] : 0;
        sC[j] = excl;
        int n = lo + j;
        if (n < N) {
            off[n] = (unsigned)(base + excl);
            if (cnt) {
                cnt[n] = (unsigned)sH[j];
                dinv[n] = rsqrtf((float)sH[j] + 1.f);
            }
        }
    }
    if (threadIdx.x == 0 && b == NBUK - 1) off[N] = (unsigned)E;
    __syncthreads();
    for (int i = base + threadIdx.x; i < end; i += 256) {
        int2 p = bucketed[i];
        int pos = base + atomicAdd(&sC[p.x & (BW - 1)], 1);
        pay[pos] = p.y;
    }
}

// ---------- K7: h0s = dinv[n] * (x[n] @ W) ----------
// R4 design: W in LDS (32 KB only -> ~5 blocks/CU), A operand read DIRECTLY
// from global: all 16 tx-lanes of a group share the x address -> HW broadcast,
// each x line fetched once per block, L1-served across the 4 k-substeps.
// (R3 lesson: do NOT stream bulk x via scalar pipe; R2 lesson: staging both
// A and W in LDS makes the per-CU LDS pipe the bottleneck at 2 blocks/CU.)
// 128 rows/block, 8 rows x 4 cols per thread: LDS-pipe cyc/CU ~7.8us < FMA 10.4us.
__global__ __launch_bounds__(256) void k_gemm(const float* __restrict__ x,
                                              const float* __restrict__ W,
                                              const float* __restrict__ dinv,
                                              float* __restrict__ h0s, int N) {
    __shared__ float Ws[DIN * DOUT];
    for (int i = threadIdx.x; i < DIN * DOUT / 4; i += 256)
        ((float4*)Ws)[i] = ((const float4*)W)[i];
    __syncthreads();

    int tx = threadIdx.x & 15;      // 4-col group
    int ty = threadIdx.x >> 4;      // 8-row group
    int r0 = blockIdx.x * GTN + ty * 8;
    if (r0 >= N) return;
    const float* xr = x + (size_t)r0 * DIN;

    float acc[8][4] = {};
    if (r0 + 8 <= N) {
        for (int k = 0; k < DIN; k += 4) {
            float4 w0 = *((float4*)(Ws + (k + 0) * DOUT + 4 * tx));
            float4 w1 = *((float4*)(Ws + (k + 1) * DOUT + 4 * tx));
            float4 w2 = *((float4*)(Ws + (k + 2) * DOUT + 4 * tx));
            float4 w3 = *((float4*)(Ws + (k + 3) * DOUT + 4 * tx));
#pragma unroll
            for (int j = 0; j < 8; ++j) {
                float4 a = *(const float4*)(xr + (size_t)j * DIN + k);  // 16-lane broadcast
                acc[j][0] = fmaf(a.x, w0.x, fmaf(a.y, w1.x, fmaf(a.z, w2.x, fmaf(a.w, w3.x, acc[j][0]))));
                acc[j][1] = fmaf(a.x, w0.y, fmaf(a.y, w1.y, fmaf(a.z, w2.y, fmaf(a.w, w3.y, acc[j][1]))));
                acc[j][2] = fmaf(a.x, w0.z, fmaf(a.y, w1.z, fmaf(a.z, w2.z, fmaf(a.w, w3.z, acc[j][2]))));
                acc[j][3] = fmaf(a.x, w0.w, fmaf(a.y, w1.w, fmaf(a.z, w2.w, fmaf(a.w, w3.w, acc[j][3]))));
            }
        }
#pragma unroll
        for (int j = 0; j < 8; ++j) {
            int n = r0 + j;
            float dv = dinv[n];
            float4 o = make_float4(acc[j][0] * dv, acc[j][1] * dv,
                                   acc[j][2] * dv, acc[j][3] * dv);
            *((float4*)(h0s + (size_t)n * DOUT + 4 * tx)) = o;
        }
    } else {
        // tail: guard per row
        for (int k = 0; k < DIN; k += 4) {
            float4 w0 = *((float4*)(Ws + (k + 0) * DOUT + 4 * tx));
            float4 w1 = *((float4*)(Ws + (k + 1) * DOUT + 4 * tx));
            float4 w2 = *((float4*)(Ws + (k + 2) * DOUT + 4 * tx));
            float4 w3 = *((float4*)(Ws + (k + 3) * DOUT + 4 * tx));
#pragma unroll
            for (int j = 0; j < 8; ++j) {
                if (r0 + j < N) {
                    float4 a = *(const float4*)(xr + (size_t)j * DIN + k);
                    acc[j][0] = fmaf(a.x, w0.x, fmaf(a.y, w1.x, fmaf(a.z, w2.x, fmaf(a.w, w3.x, acc[j][0]))));
                    acc[j][1] = fmaf(a.x, w0.y, fmaf(a.y, w1.y, fmaf(a.z, w2.y, fmaf(a.w, w3.y, acc[j][1]))));
                    acc[j][2] = fmaf(a.x, w0.z, fmaf(a.y, w1.z, fmaf(a.z, w2.z, fmaf(a.w, w3.z, acc[j][2]))));
                    acc[j][3] = fmaf(a.x, w0.w, fmaf(a.y, w1.w, fmaf(a.z, w2.w, fmaf(a.w, w3.w, acc[j][3]))));
                }
            }
        }
#pragma unroll
        for (int j = 0; j < 8; ++j) {
            int n = r0 + j;
            if (n < N) {
                float dv = dinv[n];
                float4 o = make_float4(acc[j][0] * dv, acc[j][1] * dv,
                                       acc[j][2] * dv, acc[j][3] * dv);
                *((float4*)(h0s + (size_t)n * DOUT + 4 * tx)) = o;
            }
        }
    }
}

// ---------- K8: gather agg + fused combine ----------
// One node per 16-lane GROUP (4 nodes/wave, 16/block). A row is exactly
// 16 lanes x float4 = 256B. Lane q preloads pay[beg+q] (covers deg<=16 in
// ONE coalesced load); edge ids then come from __shfl registers, removing
// the pay load from the dependent chain. 4 independent chains per wave.
__global__ __launch_bounds__(256) void k_agg(const unsigned* __restrict__ off,
                                             const int* __restrict__ pay,
                                             const float* __restrict__ dinv,
                                             const float* __restrict__ h0s,
                                             const float* __restrict__ b,
                                             float* __restrict__ h, int N) {
    int t = threadIdx.x;
    int grp = t >> 4;          // 0..15
    int q = t & 15;
    int n = blockIdx.x * 16 + grp;
    if (n >= N) return;
    unsigned beg = off[n], end = off[n + 1];
    float4 acc = make_float4(0.f, 0.f, 0.f, 0.f);
    for (unsigned base2 = beg; base2 < end; base2 += 16) {
        unsigned idx = base2 + q;
        int pd = (idx < end) ? pay[idx] : 0;
        int jmax = (int)min(16u, end - base2);
        int j = 0;
        for (; j + 4 <= jmax; j += 4) {
            int s0 = __shfl(pd, j + 0, 16);
            int s1 = __shfl(pd, j + 1, 16);
            int s2 = __shfl(pd, j + 2, 16);
            int s3 = __shfl(pd, j + 3, 16);
            float4 a0 = *(const float4*)(h0s + (size_t)s0 * DOUT + 4 * q);
            float4 a1 = *(const float4*)(h0s + (size_t)s1 * DOUT + 4 * q);
            float4 a2 = *(const float4*)(h0s + (size_t)s2 * DOUT + 4 * q);
            float4 a3 = *(const float4*)(h0s + (size_t)s3 * DOUT + 4 * q);
            acc.x += (a0.x + a1.x) + (a2.x + a3.x);
            acc.y += (a0.y + a1.y) + (a2.y + a3.y);
            acc.z += (a0.z + a1.z) + (a2.z + a3.z);
            acc.w += (a0.w + a1.w) + (a2.w + a3.w);
        }
        for (; j < jmax; ++j) {
            int s = __shfl(pd, j, 16);
            float4 a = *(const float4*)(h0s + (size_t)s * DOUT + 4 * q);
            acc.x += a.x; acc.y += a.y; acc.z += a.z; acc.w += a.w;
        }
    }
    float dv = dinv[n];
    float4 hs = *(const float4*)(h0s + (size_t)n * DOUT + 4 * q);
    float4 bv = *(const float4*)(b + 4 * q);
    float4 o;
    o.x = dv * (acc.x + hs.x) + bv.x;
    o.y = dv * (acc.y + hs.y) + bv.y;
    o.z = dv * (acc.z + hs.z) + bv.z;
    o.w = dv * (acc.w + hs.w) + bv.w;
    *(float4*)(h + (size_t)n * DOUT + 4 * q) = o;
}

// ---------- K9: gather energy + S (same group-per-node structure) ----------
__global__ __launch_bounds__(256) void k_energy(const unsigned* __restrict__ off,
                                                const int* __restrict__ pay,
                                                const float* __restrict__ h,
                                                float* __restrict__ e,
                                                float* __restrict__ S, int N) {
    int t = threadIdx.x;
    int grp = t >> 4;
    int q = t & 15;
    int n = blockIdx.x * 16 + grp;
    if (n >= N) return;
    unsigned beg = off[n], end = off[n + 1];
    float4 hm = *(const float4*)(h + (size_t)n * DOUT + 4 * q);
    float4 Sa = make_float4(0.f, 0.f, 0.f, 0.f);
    float esum = 0.f;
    for (unsigned base2 = beg; base2 < end; base2 += 16) {
        unsigned idx = base2 + q;
        int pd = (idx < end) ? pay[idx] : 0;
        int jmax = (int)min(16u, end - base2);
        int j = 0;
        for (; j + 4 <= jmax; j += 4) {
            int s0 = __shfl(pd, j + 0, 16);
            int s1 = __shfl(pd, j + 1, 16);
            int s2 = __shfl(pd, j + 2, 16);
            int s3 = __shfl(pd, j + 3, 16);
            float4 a0 = *(const float4*)(h + (size_t)s0 * DOUT + 4 * q);
            float4 a1 = *(const float4*)(h + (size_t)s1 * DOUT + 4 * q);
            float4 a2 = *(const float4*)(h + (size_t)s2 * DOUT + 4 * q);
            float4 a3 = *(const float4*)(h + (size_t)s3 * DOUT + 4 * q);
            Sa.x += (a0.x + a1.x) + (a2.x + a3.x);
            Sa.y += (a0.y + a1.y) + (a2.y + a3.y);
            Sa.z += (a0.z + a1.z) + (a2.z + a3.z);
            Sa.w += (a0.w + a1.w) + (a2.w + a3.w);
            float dx, dy, dz, dw;
            dx = hm.x - a0.x; dy = hm.y - a0.y; dz = hm.z - a0.z; dw = hm.w - a0.w;
            esum += dx * dx + dy * dy + dz * dz + dw * dw;
            dx = hm.x - a1.x; dy = hm.y - a1.y; dz = hm.z - a1.z; dw = hm.w - a1.w;
            esum += dx * dx + dy * dy + dz * dz + dw * dw;
            dx = hm.x - a2.x; dy = hm.y - a2.y; dz = hm.z - a2.z; dw = hm.w - a2.w;
            esum += dx * dx + dy * dy + dz * dz + dw * dw;
            dx = hm.x - a3.x; dy = hm.y - a3.y; dz = hm.z - a3.z; dw = hm.w - a3.w;
            esum += dx * dx + dy * dy + dz * dz + dw * dw;
        }
        for (; j < jmax; ++j) {
            int s = __shfl(pd, j, 16);
            float4 a = *(const float4*)(h + (size_t)s * DOUT + 4 * q);
            Sa.x += a.x; Sa.y += a.y; Sa.z += a.z; Sa.w += a.w;
            float dx = hm.x - a.x, dy = hm.y - a.y, dz = hm.z - a.z, dw = hm.w - a.w;
            esum += dx * dx + dy * dy + dz * dz + dw * dw;
        }
    }
#pragma unroll
    for (int m = 1; m <= 8; m <<= 1) esum += __shfl_xor(esum, m, 16);
    if (q == 0) e[n] = esum;
    *(float4*)(S + (size_t)n * DOUT + 4 * q) = Sa;
}

// ---------- K10: per-block softmax partials (m, Z, M) ----------
__global__ __launch_bounds__(256) void k_stats1(const float* __restrict__ e,
                                                const float* __restrict__ Tptr,
                                                float* __restrict__ part, int N) {
    float T = *Tptr;
    float m = -3.4e38f;
    int i0 = blockIdx.x * 256 + threadIdx.x;
    int stride = gridDim.x * 256;
    for (int i = i0; i < N; i += stride) m = fmaxf(m, -e[i] / T);
    __shared__ float sm[256];
    sm[threadIdx.x] = m;
    __syncthreads();
    for (int s = 128; s > 0; s >>= 1) {
        if (threadIdx.x < s) sm[threadIdx.x] = fmaxf(sm[threadIdx.x], sm[threadIdx.x + s]);
        __syncthreads();
    }
    float bm = sm[0];
    __syncthreads();
    float z = 0.f, mm = 0.f;
    for (int i = i0; i < N; i += stride) {
        float t = -e[i] / T - bm;
        float w = __expf(t);
        z += w;
        mm += w * t;
    }
    __shared__ float sz[256], sM[256];
    sz[threadIdx.x] = z;
    sM[threadIdx.x] = mm;
    __syncthreads();
    for (int s = 128; s > 0; s >>= 1) {
        if (threadIdx.x < s) {
            sz[threadIdx.x] += sz[threadIdx.x + s];
            sM[threadIdx.x] += sM[threadIdx.x + s];
        }
        __syncthreads();
    }
    if (threadIdx.x == 0) {
        part[blockIdx.x * 3 + 0] = bm;
        part[blockIdx.x * 3 + 1] = sz[0];
        part[blockIdx.x * 3 + 2] = sM[0];
    }
}

// ---------- K11: merge partials -> st = {m, Z, M} ----------
__global__ __launch_bounds__(256) void k_stats2(const float* __restrict__ part,
                                                float* __restrict__ st, int P) {
    __shared__ float sm[256];
    float m = -3.4e38f;
    for (int i = threadIdx.x; i < P; i += 256) m = fmaxf(m, part[3 * i]);
    sm[threadIdx.x] = m;
    __syncthreads();
    for (int s = 128; s > 0; s >>= 1) {
        if (threadIdx.x < s) sm[threadIdx.x] = fmaxf(sm[threadIdx.x], sm[threadIdx.x + s]);
        __syncthreads();
    }
    float gm = sm[0];
    __syncthreads();
    float Z = 0.f, M = 0.f;
    for (int i = threadIdx.x; i < P; i += 256) {
        float mb = part[3 * i], zb = part[3 * i + 1], Mb = part[3 * i + 2];
        float d = mb - gm, eb = __expf(d);
        Z += eb * zb;
        M += eb * (Mb + d * zb);
    }
    __shared__ float sz[256], sM2[256];
    sz[threadIdx.x] = Z;
    sM2[threadIdx.x] = M;
    __syncthreads();
    for (int s = 128; s > 0; s >>= 1) {
        if (threadIdx.x < s) {
            sz[threadIdx.x] += sz[threadIdx.x + s];
            sM2[threadIdx.x] += sM2[threadIdx.x + s];
        }
        __syncthreads();
    }
    if (threadIdx.x == 0) {
        st[0] = gm;
        st[1] = sz[0];
        st[2] = sM2[0];
    }
}

// ---------- K12: c_n = p_n * (logp_n + H) ----------
__global__ __launch_bounds__(256) void k_coef(const float* __restrict__ e,
                                              const float* __restrict__ Tptr,
                                              const float* __restrict__ st,
                                              float* __restrict__ c, int N) {
    int n = blockIdx.x * 256 + threadIdx.x;
    if (n >= N) return;
    float T = *Tptr;
    float gm = st[0], Z = st[1], M = st[2];
    float logZ = logf(Z);
    float H = logZ - M / Z;
    float t = -e[n] / T - gm;
    float lp = t - logZ;
    c[n] = expf(lp) * (lp + H);
}

// ---------- K13: out-CSR gather of A,B + fused final ----------
// group-per-node: c[pay] pre-gathered alongside pay, both shfl-broadcast.
// A replicates across the group; B accumulates each lane's float4 slice.
// No cross-group reduction needed at all.
__global__ __launch_bounds__(256) void k_grad_final(const unsigned* __restrict__ off,
                                                    const int* __restrict__ pay,
                                                    const float* __restrict__ c,
                                                    const float* __restrict__ h,
                                                    const float* __restrict__ S,
                                                    const unsigned* __restrict__ cnt,
                                                    const float* __restrict__ wptr,
                                                    float* __restrict__ out, int N) {
    int t = threadIdx.x;
    int grp = t >> 4;
    int q = t & 15;
    int n = blockIdx.x * 16 + grp;
    if (n >= N) return;
    unsigned beg = off[n], end = off[n + 1];
    float A = 0.f;
    float4 B = make_float4(0.f, 0.f, 0.f, 0.f);
    for (unsigned base2 = beg; base2 < end; base2 += 16) {
        unsigned idx = base2 + q;
        int pd = 0;
        float cv = 0.f;
        if (idx < end) {
            pd = pay[idx];
            cv = c[pd];
        }
        int jmax = (int)min(16u, end - base2);
        int j = 0;
        for (; j + 4 <= jmax; j += 4) {
            int s0 = __shfl(pd, j + 0, 16);
            int s1 = __shfl(pd, j + 1, 16);
            int s2 = __shfl(pd, j + 2, 16);
            int s3 = __shfl(pd, j + 3, 16);
            float c0 = __shfl(cv, j + 0, 16);
            float c1 = __shfl(cv, j + 1, 16);
            float c2 = __shfl(cv, j + 2, 16);
            float c3 = __shfl(cv, j + 3, 16);
            float4 a0 = *(const float4*)(h + (size_t)s0 * DOUT + 4 * q);
            float4 a1 = *(const float4*)(h + (size_t)s1 * DOUT + 4 * q);
            float4 a2 = *(const float4*)(h + (size_t)s2 * DOUT + 4 * q);
            float4 a3 = *(const float4*)(h + (size_t)s3 * DOUT + 4 * q);
            A += (c0 + c1) + (c2 + c3);
            B.x = fmaf(c0, a0.x, fmaf(c1, a1.x, fmaf(c2, a2.x, fmaf(c3, a3.x, B.x))));
            B.y = fmaf(c0, a0.y, fmaf(c1, a1.y, fmaf(c2, a2.y, fmaf(c3, a3.y, B.y))));
            B.z = fmaf(c0, a0.z, fmaf(c1, a1.z, fmaf(c2, a2.z, fmaf(c3, a3.z, B.z))));
            B.w = fmaf(c0, a0.w, fmaf(c1, a1.w, fmaf(c2, a2.w, fmaf(c3, a3.w, B.w))));
        }
        for (; j < jmax; ++j) {
            int s = __shfl(pd, j, 16);
            float cj = __shfl(cv, j, 16);
            float4 a = *(const float4*)(h + (size_t)s * DOUT + 4 * q);
            A += cj;
            B.x = fmaf(cj, a.x, B.x);
            B.y = fmaf(cj, a.y, B.y);
            B.z = fmaf(cj, a.z, B.z);
            B.w = fmaf(cj, a.w, B.w);
        }
    }
    size_t idx4 = (size_t)n * DOUT + 4 * q;
    float4 hm = *(const float4*)(h + idx4);
    float4 Sv = *(const float4*)(S + idx4);
    float cn = c[n];
    float cc = (float)cnt[n];
    float w = *wptr;
    float4 o;
    o.x = hm.x + w * (2.f * cn * (cc * hm.x - Sv.x) + 2.f * (A * hm.x - B.x));
    o.y = hm.y + w * (2.f * cn * (cc * hm.y - Sv.y) + 2.f * (A * hm.y - B.y));
    o.z = hm.z + w * (2.f * cn * (cc * hm.z - Sv.z) + 2.f * (A * hm.z - B.z));
    o.w = hm.w + w * (2.f * cn * (cc * hm.w - Sv.w) + 2.f * (A * hm.w - B.w));
    *(float4*)(out + idx4) = o;
}

extern "C" void kernel_launch(void* const* d_in, const int* in_sizes, int n_in,
                              void* d_out, int out_size, void* d_ws, size_t ws_size,
                              hipStream_t stream) {
    const float* x    = (const float*)d_in[0];
    const int*   ei   = (const int*)d_in[1];
    const float* wptr = (const float*)d_in[2];
    const float* Tptr = (const float*)d_in[3];
    const float* W    = (const float*)d_in[4];
    const float* b    = (const float*)d_in[5];
    float* out = (float*)d_out;

    const int N  = in_sizes[0] / DIN;   // 100000
    const int E  = in_sizes[1] / 2;     // 1000000
    const int NE = N * DOUT;
    const int* src = ei;
    const int* dst = ei + E;

    const int NBUK = (N + BW - 1) / BW;         // 196
    const int NC   = (E + EPC - 1) / EPC;       // 245
    const int M    = NBUK * NC;
    const int M2   = 2 * M;
    const int NBs  = (M2 + 255) / 256;          // <= 1024

    // workspace layout
    float*    h0s  = (float*)d_ws;                    // NE (reused as S later)
    float*    h    = h0s + NE;                        // NE
    int2*     bkt  = (int2*)(h + NE);                 // E int2 (8 MB, reused per dir)
    int*      pay1 = (int*)(bkt + E);                 // E (in-CSR payload: src ids)
    int*      pay2 = pay1 + E;                        // E (out-CSR payload: dst ids)
    unsigned* counts = (unsigned*)(pay2 + E);         // 2*M
    unsigned* bsum = counts + M2;                     // <=1024
    unsigned* off1 = bsum + 1024;                     // N+1
    unsigned* off2 = off1 + N + 1;                    // N+1
    unsigned* cnt  = off2 + N + 1;                    // N
    float*    e    = (float*)(cnt + N);               // N
    float*    c    = e + N;                           // N
    float*    dinv = c + N;                           // N
    float*    part = dinv + N;                        // 3*NSTATB
    float*    st   = part + 3 * NSTATB;               // 3
    float*    S    = h0s;                             // reuse after k_agg

    const int nodeG = (N + 15) / 16;    // 16 nodes per 256-thread block
    const int nodeBlocks = (N + 255) / 256;

    // build both direction counts + one combined scan
    k_countboth<<<NC, 256, 0, stream>>>(src, dst, counts, NBUK, NC, E);
    k_scanA<<<NBs, 256, 0, stream>>>(counts, bsum, M2);
    k_scan2<<<1, 1024, 0, stream>>>(bsum, NBs);
    k_scanC<<<NBs, 256, 0, stream>>>(counts, bsum, M2);

    // direction 0: in-CSR (key=dst, payload=src) -> off1/pay1 + cnt/dinv
    k_bucket<<<NC, 256, 0, stream>>>(dst, src, counts, 0, 0u, bkt, NBUK, NC, E);
    k_csr<<<NBUK, 256, 0, stream>>>(bkt, counts, off1, pay1, cnt, dinv,
                                    0, 0u, NBUK, NC, N, E);
    // direction 1: out-CSR (key=src, payload=dst) -> off2/pay2
    k_bucket<<<NC, 256, 0, stream>>>(src, dst, counts, M, (unsigned)E, bkt, NBUK, NC, E);
    k_csr<<<NBUK, 256, 0, stream>>>(bkt, counts, off2, pay2, nullptr, nullptr,
                                    M, (unsigned)E, NBUK, NC, N, E);

    k_gemm<<<(N + GTN - 1) / GTN, 256, 0, stream>>>(x, W, dinv, h0s, N);
    k_agg<<<nodeG, 256, 0, stream>>>(off1, pay1, dinv, h0s, b, h, N);
    k_energy<<<nodeG, 256, 0, stream>>>(off1, pay1, h, e, S, N);
    k_stats1<<<NSTATB, 256, 0, stream>>>(e, Tptr, part, N);
    k_stats2<<<1, 256, 0, stream>>>(part, st, NSTATB);
    k_coef<<<nodeBlocks, 256, 0, stream>>>(e, Tptr, st, c, N);
    k_grad_final<<<nodeG, 256, 0, stream>>>(off2, pay2, c, h, S, cnt, wptr, out, N);
}

// Round 5
// 329.725 us; speedup vs baseline: 1.2465x; 1.0125x over previous
//
#include <hip/hip_runtime.h>

#define DIN  128
#define DOUT 64
#define GTN  64     // rows per gemm block (256 thr = 16 col-groups x 16 row-groups of 4)
#define BW   512    // nodes per bucket (power of 2)
#define BSH  9      // log2(BW)
#define EPC  4096   // edges per chunk
#define NSTATB 400  // stat partial blocks

// ---------- K1: per-chunk, per-bucket histograms for BOTH directions ----------
__global__ __launch_bounds__(256) void k_countboth(const int* __restrict__ src,
                                                   const int* __restrict__ dst,
                                                   unsigned* __restrict__ counts,
                                                   int NBUK, int NC, int E) {
    __shared__ int h0[256], h1[256];
    for (int j = threadIdx.x; j < NBUK; j += 256) { h0[j] = 0; h1[j] = 0; }
    __syncthreads();
    int start = blockIdx.x * EPC;
    int end = min(start + EPC, E);
    for (int i = start + threadIdx.x; i < end; i += 256) {
        atomicAdd(&h0[dst[i] >> BSH], 1);
        atomicAdd(&h1[src[i] >> BSH], 1);
    }
    __syncthreads();
    int M = NBUK * NC;
    for (int j = threadIdx.x; j < NBUK; j += 256) {
        counts[j * NC + blockIdx.x]     = (unsigned)h0[j];
        counts[M + j * NC + blockIdx.x] = (unsigned)h1[j];
    }
}

// ---------- generic 3-kernel exclusive scan ----------
__global__ __launch_bounds__(256) void k_scanA(const unsigned* __restrict__ data,
                                               unsigned* __restrict__ bsums, int n) {
    __shared__ unsigned s[256];
    int i = blockIdx.x * 256 + threadIdx.x;
    s[threadIdx.x] = (i < n) ? data[i] : 0u;
    __syncthreads();
    for (int st = 128; st > 0; st >>= 1) {
        if (threadIdx.x < st) s[threadIdx.x] += s[threadIdx.x + st];
        __syncthreads();
    }
    if (threadIdx.x == 0) bsums[blockIdx.x] = s[0];
}

__global__ __launch_bounds__(1024) void k_scan2(unsigned* __restrict__ bsums, int NB) {
    __shared__ unsigned s[1024];
    int tid = threadIdx.x;
    unsigned v = (tid < NB) ? bsums[tid] : 0u;
    s[tid] = v;
    __syncthreads();
    for (int st = 1; st < 1024; st <<= 1) {
        unsigned t = (tid >= st) ? s[tid - st] : 0u;
        __syncthreads();
        s[tid] += t;
        __syncthreads();
    }
    if (tid < NB) bsums[tid] = s[tid] - v;   // exclusive
}

__global__ __launch_bounds__(256) void k_scanC(unsigned* __restrict__ data,
                                               const unsigned* __restrict__ bsums, int n) {
    __shared__ unsigned s[256];
    int i = blockIdx.x * 256 + threadIdx.x;
    unsigned v = (i < n) ? data[i] : 0u;
    s[threadIdx.x] = v;
    __syncthreads();
    for (int st = 1; st < 256; st <<= 1) {
        unsigned t = (threadIdx.x >= st) ? s[threadIdx.x - st] : 0u;
        __syncthreads();
        s[threadIdx.x] += t;
        __syncthreads();
    }
    if (i < n) data[i] = s[threadIdx.x] - v + bsums[blockIdx.x];
}

// ---------- K5: bucket-major reorder (coalesced block-private segments) ----------
__global__ __launch_bounds__(256) void k_bucket(const int* __restrict__ key,
                                                const int* __restrict__ other,
                                                const unsigned* __restrict__ counts,
                                                int dirOff, unsigned dirBase,
                                                int2* __restrict__ bucketed,
                                                int NBUK, int NC, int E) {
    __shared__ int cur[256];
    for (int j = threadIdx.x; j < NBUK; j += 256)
        cur[j] = (int)(counts[dirOff + j * NC + blockIdx.x] - dirBase);
    __syncthreads();
    int start = blockIdx.x * EPC;
    int end = min(start + EPC, E);
    for (int i = start + threadIdx.x; i < end; i += 256) {
        int k = key[i], o = other[i];
        int pos = atomicAdd(&cur[k >> BSH], 1);
        bucketed[pos] = make_int2(k, o);
    }
}

// ---------- K6: per-bucket CSR finalize — degrees, offsets, private scatter ----------
__global__ __launch_bounds__(256) void k_csr(const int2* __restrict__ bucketed,
                                             const unsigned* __restrict__ counts,
                                             unsigned* __restrict__ off,
                                             int* __restrict__ pay,
                                             unsigned* __restrict__ cnt,
                                             float* __restrict__ dinv,
                                             int dirOff, unsigned dirBase,
                                             int NBUK, int NC, int N, int E) {
    __shared__ int sH[BW];
    __shared__ int sS[2][BW];
    __shared__ int sC[BW];
    int b = blockIdx.x;
    int base = (int)(counts[dirOff + b * NC] - dirBase);
    int end  = (b + 1 < NBUK) ? (int)(counts[dirOff + (b + 1) * NC] - dirBase) : E;

    for (int j = threadIdx.x; j < BW; j += 256) sH[j] = 0;
    __syncthreads();
    for (int i = base + threadIdx.x; i < end; i += 256)
        atomicAdd(&sH[bucketed[i].x & (BW - 1)], 1);
    __syncthreads();
    for (int j = threadIdx.x; j < BW; j += 256) sS[0][j] = sH[j];
    __syncthreads();
    int pin = 0;
    for (int st = 1; st < BW; st <<= 1) {
        for (int j = threadIdx.x; j < BW; j += 256) {
            int v = sS[pin][j];
            if (j >= st) v += sS[pin][j - st];
            sS[pin ^ 1][j] = v;
        }
        __syncthreads();
        pin ^= 1;
    }
    int lo = b * BW;
    for (int j = threadIdx.x; j < BW; j += 256) {
        int excl = j ? sS[pin][j - 1] : 0;
        sC[j] = excl;
        int n = lo + j;
        if (n < N) {
            off[n] = (unsigned)(base + excl);
            if (cnt) {
                cnt[n] = (unsigned)sH[j];
                dinv[n] = rsqrtf((float)sH[j] + 1.f);
            }
        }
    }
    if (threadIdx.x == 0 && b == NBUK - 1) off[N] = (unsigned)E;
    __syncthreads();
    for (int i = base + threadIdx.x; i < end; i += 256) {
        int2 p = bucketed[i];
        int pos = base + atomicAdd(&sC[p.x & (BW - 1)], 1);
        pay[pos] = p.y;
    }
}

// ---------- K7: h0s = dinv[n] * (x[n] @ W) ----------
// R5: W in LDS (32 KB). x read directly from global with 16-lane broadcast.
// R4 post-mortem: 128-row tile -> 782 blocks = 3 blocks/CU (grid-limited
// occupancy 19%) and zero load-ahead -> VALU stalled 75% on x latency.
// Fix: 64-row tile (1563 blocks, LDS-capped 5 blocks/CU = 20 waves) +
// double-buffered x prefetch (next k-step's 4 rows in flight under FMAs).
__global__ __launch_bounds__(256) void k_gemm(const float* __restrict__ x,
                                              const float* __restrict__ W,
                                              const float* __restrict__ dinv,
                                              float* __restrict__ h0s, int N) {
    __shared__ float Ws[DIN * DOUT];
    for (int i = threadIdx.x; i < DIN * DOUT / 4; i += 256)
        ((float4*)Ws)[i] = ((const float4*)W)[i];

    int tx = threadIdx.x & 15;      // 4-col group
    int ty = threadIdx.x >> 4;      // 4-row group
    int r0 = blockIdx.x * GTN + ty * 4;
    __syncthreads();
    if (r0 >= N) return;
    const float* xr = x + (size_t)r0 * DIN;

    float acc[4][4] = {};

#define FMA4(aj, w0, w1, w2, w3, j)                                            \
    acc[j][0] = fmaf(aj.x, w0.x, fmaf(aj.y, w1.x, fmaf(aj.z, w2.x, fmaf(aj.w, w3.x, acc[j][0])))); \
    acc[j][1] = fmaf(aj.x, w0.y, fmaf(aj.y, w1.y, fmaf(aj.z, w2.y, fmaf(aj.w, w3.y, acc[j][1])))); \
    acc[j][2] = fmaf(aj.x, w0.z, fmaf(aj.y, w1.z, fmaf(aj.z, w2.z, fmaf(aj.w, w3.z, acc[j][2])))); \
    acc[j][3] = fmaf(aj.x, w0.w, fmaf(aj.y, w1.w, fmaf(aj.z, w2.w, fmaf(aj.w, w3.w, acc[j][3]))));

    if (r0 + 4 <= N) {
        float4 a0[4], a1[4];
#pragma unroll
        for (int j = 0; j < 4; ++j) a0[j] = *(const float4*)(xr + (size_t)j * DIN);
#pragma unroll 2
        for (int k = 0; k < DIN; k += 8) {
            // stage B prefetch (k+4) while FMA-ing stage A (k)
#pragma unroll
            for (int j = 0; j < 4; ++j)
                a1[j] = *(const float4*)(xr + (size_t)j * DIN + k + 4);
            {
                float4 w0 = *((float4*)(Ws + (k + 0) * DOUT + 4 * tx));
                float4 w1 = *((float4*)(Ws + (k + 1) * DOUT + 4 * tx));
                float4 w2 = *((float4*)(Ws + (k + 2) * DOUT + 4 * tx));
                float4 w3 = *((float4*)(Ws + (k + 3) * DOUT + 4 * tx));
                FMA4(a0[0], w0, w1, w2, w3, 0)
                FMA4(a0[1], w0, w1, w2, w3, 1)
                FMA4(a0[2], w0, w1, w2, w3, 2)
                FMA4(a0[3], w0, w1, w2, w3, 3)
            }
            // stage A prefetch (k+8) while FMA-ing stage B (k+4)
            if (k + 8 < DIN) {
#pragma unroll
                for (int j = 0; j < 4; ++j)
                    a0[j] = *(const float4*)(xr + (size_t)j * DIN + k + 8);
            }
            {
                float4 w0 = *((float4*)(Ws + (k + 4) * DOUT + 4 * tx));
                float4 w1 = *((float4*)(Ws + (k + 5) * DOUT + 4 * tx));
                float4 w2 = *((float4*)(Ws + (k + 6) * DOUT + 4 * tx));
                float4 w3 = *((float4*)(Ws + (k + 7) * DOUT + 4 * tx));
                FMA4(a1[0], w0, w1, w2, w3, 0)
                FMA4(a1[1], w0, w1, w2, w3, 1)
                FMA4(a1[2], w0, w1, w2, w3, 2)
                FMA4(a1[3], w0, w1, w2, w3, 3)
            }
        }
#pragma unroll
        for (int j = 0; j < 4; ++j) {
            int n = r0 + j;
            float dv = dinv[n];
            float4 o = make_float4(acc[j][0] * dv, acc[j][1] * dv,
                                   acc[j][2] * dv, acc[j][3] * dv);
            *((float4*)(h0s + (size_t)n * DOUT + 4 * tx)) = o;
        }
    } else {
        // tail: guarded, non-pipelined
        for (int k = 0; k < DIN; k += 4) {
            float4 w0 = *((float4*)(Ws + (k + 0) * DOUT + 4 * tx));
            float4 w1 = *((float4*)(Ws + (k + 1) * DOUT + 4 * tx));
            float4 w2 = *((float4*)(Ws + (k + 2) * DOUT + 4 * tx));
            float4 w3 = *((float4*)(Ws + (k + 3) * DOUT + 4 * tx));
#pragma unroll
            for (int j = 0; j < 4; ++j) {
                if (r0 + j < N) {
                    float4 a = *(const float4*)(xr + (size_t)j * DIN + k);
                    FMA4(a, w0, w1, w2, w3, j)
                }
            }
        }
#pragma unroll
        for (int j = 0; j < 4; ++j) {
            int n = r0 + j;
            if (n < N) {
                float dv = dinv[n];
                float4 o = make_float4(acc[j][0] * dv, acc[j][1] * dv,
                                       acc[j][2] * dv, acc[j][3] * dv);
                *((float4*)(h0s + (size_t)n * DOUT + 4 * tx)) = o;
            }
        }
    }
#undef FMA4
}

// ---------- K8: gather agg + fused combine ----------
// One node per 16-lane GROUP (4 nodes/wave, 16/block). A row is exactly
// 16 lanes x float4 = 256B. Lane q preloads pay[beg+q] (covers deg<=16 in
// ONE coalesced load); edge ids then come from __shfl registers, removing
// the pay load from the dependent chain. 4 independent chains per wave.
__global__ __launch_bounds__(256) void k_agg(const unsigned* __restrict__ off,
                                             const int* __restrict__ pay,
                                             const float* __restrict__ dinv,
                                             const float* __restrict__ h0s,
                                             const float* __restrict__ b,
                                             float* __restrict__ h, int N) {
    int t = threadIdx.x;
    int grp = t >> 4;          // 0..15
    int q = t & 15;
    int n = blockIdx.x * 16 + grp;
    if (n >= N) return;
    unsigned beg = off[n], end = off[n + 1];
    float4 acc = make_float4(0.f, 0.f, 0.f, 0.f);
    for (unsigned base2 = beg; base2 < end; base2 += 16) {
        unsigned idx = base2 + q;
        int pd = (idx < end) ? pay[idx] : 0;
        int jmax = (int)min(16u, end - base2);
        int j = 0;
        for (; j + 4 <= jmax; j += 4) {
            int s0 = __shfl(pd, j + 0, 16);
            int s1 = __shfl(pd, j + 1, 16);
            int s2 = __shfl(pd, j + 2, 16);
            int s3 = __shfl(pd, j + 3, 16);
            float4 a0 = *(const float4*)(h0s + (size_t)s0 * DOUT + 4 * q);
            float4 a1 = *(const float4*)(h0s + (size_t)s1 * DOUT + 4 * q);
            float4 a2 = *(const float4*)(h0s + (size_t)s2 * DOUT + 4 * q);
            float4 a3 = *(const float4*)(h0s + (size_t)s3 * DOUT + 4 * q);
            acc.x += (a0.x + a1.x) + (a2.x + a3.x);
            acc.y += (a0.y + a1.y) + (a2.y + a3.y);
            acc.z += (a0.z + a1.z) + (a2.z + a3.z);
            acc.w += (a0.w + a1.w) + (a2.w + a3.w);
        }
        for (; j < jmax; ++j) {
            int s = __shfl(pd, j, 16);
            float4 a = *(const float4*)(h0s + (size_t)s * DOUT + 4 * q);
            acc.x += a.x; acc.y += a.y; acc.z += a.z; acc.w += a.w;
        }
    }
    float dv = dinv[n];
    float4 hs = *(const float4*)(h0s + (size_t)n * DOUT + 4 * q);
    float4 bv = *(const float4*)(b + 4 * q);
    float4 o;
    o.x = dv * (acc.x + hs.x) + bv.x;
    o.y = dv * (acc.y + hs.y) + bv.y;
    o.z = dv * (acc.z + hs.z) + bv.z;
    o.w = dv * (acc.w + hs.w) + bv.w;
    *(float4*)(h + (size_t)n * DOUT + 4 * q) = o;
}

// ---------- K9: gather energy + S (same group-per-node structure) ----------
__global__ __launch_bounds__(256) void k_energy(const unsigned* __restrict__ off,
                                                const int* __restrict__ pay,
                                                const float* __restrict__ h,
                                                float* __restrict__ e,
                                                float* __restrict__ S, int N) {
    int t = threadIdx.x;
    int grp = t >> 4;
    int q = t & 15;
    int n = blockIdx.x * 16 + grp;
    if (n >= N) return;
    unsigned beg = off[n], end = off[n + 1];
    float4 hm = *(const float4*)(h + (size_t)n * DOUT + 4 * q);
    float4 Sa = make_float4(0.f, 0.f, 0.f, 0.f);
    float esum = 0.f;
    for (unsigned base2 = beg; base2 < end; base2 += 16) {
        unsigned idx = base2 + q;
        int pd = (idx < end) ? pay[idx] : 0;
        int jmax = (int)min(16u, end - base2);
        int j = 0;
        for (; j + 4 <= jmax; j += 4) {
            int s0 = __shfl(pd, j + 0, 16);
            int s1 = __shfl(pd, j + 1, 16);
            int s2 = __shfl(pd, j + 2, 16);
            int s3 = __shfl(pd, j + 3, 16);
            float4 a0 = *(const float4*)(h + (size_t)s0 * DOUT + 4 * q);
            float4 a1 = *(const float4*)(h + (size_t)s1 * DOUT + 4 * q);
            float4 a2 = *(const float4*)(h + (size_t)s2 * DOUT + 4 * q);
            float4 a3 = *(const float4*)(h + (size_t)s3 * DOUT + 4 * q);
            Sa.x += (a0.x + a1.x) + (a2.x + a3.x);
            Sa.y += (a0.y + a1.y) + (a2.y + a3.y);
            Sa.z += (a0.z + a1.z) + (a2.z + a3.z);
            Sa.w += (a0.w + a1.w) + (a2.w + a3.w);
            float dx, dy, dz, dw;
            dx = hm.x - a0.x; dy = hm.y - a0.y; dz = hm.z - a0.z; dw = hm.w - a0.w;
            esum += dx * dx + dy * dy + dz * dz + dw * dw;
            dx = hm.x - a1.x; dy = hm.y - a1.y; dz = hm.z - a1.z; dw = hm.w - a1.w;
            esum += dx * dx + dy * dy + dz * dz + dw * dw;
            dx = hm.x - a2.x; dy = hm.y - a2.y; dz = hm.z - a2.z; dw = hm.w - a2.w;
            esum += dx * dx + dy * dy + dz * dz + dw * dw;
            dx = hm.x - a3.x; dy = hm.y - a3.y; dz = hm.z - a3.z; dw = hm.w - a3.w;
            esum += dx * dx + dy * dy + dz * dz + dw * dw;
        }
        for (; j < jmax; ++j) {
            int s = __shfl(pd, j, 16);
            float4 a = *(const float4*)(h + (size_t)s * DOUT + 4 * q);
            Sa.x += a.x; Sa.y += a.y; Sa.z += a.z; Sa.w += a.w;
            float dx = hm.x - a.x, dy = hm.y - a.y, dz = hm.z - a.z, dw = hm.w - a.w;
            esum += dx * dx + dy * dy + dz * dz + dw * dw;
        }
    }
#pragma unroll
    for (int m = 1; m <= 8; m <<= 1) esum += __shfl_xor(esum, m, 16);
    if (q == 0) e[n] = esum;
    *(float4*)(S + (size_t)n * DOUT + 4 * q) = Sa;
}

// ---------- K10: per-block softmax partials (m, Z, M) ----------
__global__ __launch_bounds__(256) void k_stats1(const float* __restrict__ e,
                                                const float* __restrict__ Tptr,
                                                float* __restrict__ part, int N) {
    float T = *Tptr;
    float m = -3.4e38f;
    int i0 = blockIdx.x * 256 + threadIdx.x;
    int stride = gridDim.x * 256;
    for (int i = i0; i < N; i += stride) m = fmaxf(m, -e[i] / T);
    __shared__ float sm[256];
    sm[threadIdx.x] = m;
    __syncthreads();
    for (int s = 128; s > 0; s >>= 1) {
        if (threadIdx.x < s) sm[threadIdx.x] = fmaxf(sm[threadIdx.x], sm[threadIdx.x + s]);
        __syncthreads();
    }
    float bm = sm[0];
    __syncthreads();
    float z = 0.f, mm = 0.f;
    for (int i = i0; i < N; i += stride) {
        float t = -e[i] / T - bm;
        float w = __expf(t);
        z += w;
        mm += w * t;
    }
    __shared__ float sz[256], sM[256];
    sz[threadIdx.x] = z;
    sM[threadIdx.x] = mm;
    __syncthreads();
    for (int s = 128; s > 0; s >>= 1) {
        if (threadIdx.x < s) {
            sz[threadIdx.x] += sz[threadIdx.x + s];
            sM[threadIdx.x] += sM[threadIdx.x + s];
        }
        __syncthreads();
    }
    if (threadIdx.x == 0) {
        part[blockIdx.x * 3 + 0] = bm;
        part[blockIdx.x * 3 + 1] = sz[0];
        part[blockIdx.x * 3 + 2] = sM[0];
    }
}

// ---------- K11: merge partials -> st = {m, Z, M} ----------
__global__ __launch_bounds__(256) void k_stats2(const float* __restrict__ part,
                                                float* __restrict__ st, int P) {
    __shared__ float sm[256];
    float m = -3.4e38f;
    for (int i = threadIdx.x; i < P; i += 256) m = fmaxf(m, part[3 * i]);
    sm[threadIdx.x] = m;
    __syncthreads();
    for (int s = 128; s > 0; s >>= 1) {
        if (threadIdx.x < s) sm[threadIdx.x] = fmaxf(sm[threadIdx.x], sm[threadIdx.x + s]);
        __syncthreads();
    }
    float gm = sm[0];
    __syncthreads();
    float Z = 0.f, M = 0.f;
    for (int i = threadIdx.x; i < P; i += 256) {
        float mb = part[3 * i], zb = part[3 * i + 1], Mb = part[3 * i + 2];
        float d = mb - gm, eb = __expf(d);
        Z += eb * zb;
        M += eb * (Mb + d * zb);
    }
    __shared__ float sz[256], sM2[256];
    sz[threadIdx.x] = Z;
    sM2[threadIdx.x] = M;
    __syncthreads();
    for (int s = 128; s > 0; s >>= 1) {
        if (threadIdx.x < s) {
            sz[threadIdx.x] += sz[threadIdx.x + s];
            sM2[threadIdx.x] += sM2[threadIdx.x + s];
        }
        __syncthreads();
    }
    if (threadIdx.x == 0) {
        st[0] = gm;
        st[1] = sz[0];
        st[2] = sM2[0];
    }
}

// ---------- K12: c_n = p_n * (logp_n + H) ----------
__global__ __launch_bounds__(256) void k_coef(const float* __restrict__ e,
                                              const float* __restrict__ Tptr,
                                              const float* __restrict__ st,
                                              float* __restrict__ c, int N) {
    int n = blockIdx.x * 256 + threadIdx.x;
    if (n >= N) return;
    float T = *Tptr;
    float gm = st[0], Z = st[1], M = st[2];
    float logZ = logf(Z);
    float H = logZ - M / Z;
    float t = -e[n] / T - gm;
    float lp = t - logZ;
    c[n] = expf(lp) * (lp + H);
}

// ---------- K13: out-CSR gather of A,B + fused final ----------
// group-per-node: c[pay] pre-gathered alongside pay, both shfl-broadcast.
// A replicates across the group; B accumulates each lane's float4 slice.
// No cross-group reduction needed at all.
__global__ __launch_bounds__(256) void k_grad_final(const unsigned* __restrict__ off,
                                                    const int* __restrict__ pay,
                                                    const float* __restrict__ c,
                                                    const float* __restrict__ h,
                                                    const float* __restrict__ S,
                                                    const unsigned* __restrict__ cnt,
                                                    const float* __restrict__ wptr,
                                                    float* __restrict__ out, int N) {
    int t = threadIdx.x;
    int grp = t >> 4;
    int q = t & 15;
    int n = blockIdx.x * 16 + grp;
    if (n >= N) return;
    unsigned beg = off[n], end = off[n + 1];
    float A = 0.f;
    float4 B = make_float4(0.f, 0.f, 0.f, 0.f);
    for (unsigned base2 = beg; base2 < end; base2 += 16) {
        unsigned idx = base2 + q;
        int pd = 0;
        float cv = 0.f;
        if (idx < end) {
            pd = pay[idx];
            cv = c[pd];
        }
        int jmax = (int)min(16u, end - base2);
        int j = 0;
        for (; j + 4 <= jmax; j += 4) {
            int s0 = __shfl(pd, j + 0, 16);
            int s1 = __shfl(pd, j + 1, 16);
            int s2 = __shfl(pd, j + 2, 16);
            int s3 = __shfl(pd, j + 3, 16);
            float c0 = __shfl(cv, j + 0, 16);
            float c1 = __shfl(cv, j + 1, 16);
            float c2 = __shfl(cv, j + 2, 16);
            float c3 = __shfl(cv, j + 3, 16);
            float4 a0 = *(const float4*)(h + (size_t)s0 * DOUT + 4 * q);
            float4 a1 = *(const float4*)(h + (size_t)s1 * DOUT + 4 * q);
            float4 a2 = *(const float4*)(h + (size_t)s2 * DOUT + 4 * q);
            float4 a3 = *(const float4*)(h + (size_t)s3 * DOUT + 4 * q);
            A += (c0 + c1) + (c2 + c3);
            B.x = fmaf(c0, a0.x, fmaf(c1, a1.x, fmaf(c2, a2.x, fmaf(c3, a3.x, B.x))));
            B.y = fmaf(c0, a0.y, fmaf(c1, a1.y, fmaf(c2, a2.y, fmaf(c3, a3.y, B.y))));
            B.z = fmaf(c0, a0.z, fmaf(c1, a1.z, fmaf(c2, a2.z, fmaf(c3, a3.z, B.z))));
            B.w = fmaf(c0, a0.w, fmaf(c1, a1.w, fmaf(c2, a2.w, fmaf(c3, a3.w, B.w))));
        }
        for (; j < jmax; ++j) {
            int s = __shfl(pd, j, 16);
            float cj = __shfl(cv, j, 16);
            float4 a = *(const float4*)(h + (size_t)s * DOUT + 4 * q);
            A += cj;
            B.x = fmaf(cj, a.x, B.x);
            B.y = fmaf(cj, a.y, B.y);
            B.z = fmaf(cj, a.z, B.z);
            B.w = fmaf(cj, a.w, B.w);
        }
    }
    size_t idx4 = (size_t)n * DOUT + 4 * q;
    float4 hm = *(const float4*)(h + idx4);
    float4 Sv = *(const float4*)(S + idx4);
    float cn = c[n];
    float cc = (float)cnt[n];
    float w = *wptr;
    float4 o;
    o.x = hm.x + w * (2.f * cn * (cc * hm.x - Sv.x) + 2.f * (A * hm.x - B.x));
    o.y = hm.y + w * (2.f * cn * (cc * hm.y - Sv.y) + 2.f * (A * hm.y - B.y));
    o.z = hm.z + w * (2.f * cn * (cc * hm.z - Sv.z) + 2.f * (A * hm.z - B.z));
    o.w = hm.w + w * (2.f * cn * (cc * hm.w - Sv.w) + 2.f * (A * hm.w - B.w));
    *(float4*)(out + idx4) = o;
}

extern "C" void kernel_launch(void* const* d_in, const int* in_sizes, int n_in,
                              void* d_out, int out_size, void* d_ws, size_t ws_size,
                              hipStream_t stream) {
    const float* x    = (const float*)d_in[0];
    const int*   ei   = (const int*)d_in[1];
    const float* wptr = (const float*)d_in[2];
    const float* Tptr = (const float*)d_in[3];
    const float* W    = (const float*)d_in[4];
    const float* b    = (const float*)d_in[5];
    float* out = (float*)d_out;

    const int N  = in_sizes[0] / DIN;   // 100000
    const int E  = in_sizes[1] / 2;     // 1000000
    const int NE = N * DOUT;
    const int* src = ei;
    const int* dst = ei + E;

    const int NBUK = (N + BW - 1) / BW;         // 196
    const int NC   = (E + EPC - 1) / EPC;       // 245
    const int M    = NBUK * NC;
    const int M2   = 2 * M;
    const int NBs  = (M2 + 255) / 256;          // <= 1024

    // workspace layout
    float*    h0s  = (float*)d_ws;                    // NE (reused as S later)
    float*    h    = h0s + NE;                        // NE
    int2*     bkt  = (int2*)(h + NE);                 // E int2 (8 MB, reused per dir)
    int*      pay1 = (int*)(bkt + E);                 // E (in-CSR payload: src ids)
    int*      pay2 = pay1 + E;                        // E (out-CSR payload: dst ids)
    unsigned* counts = (unsigned*)(pay2 + E);         // 2*M
    unsigned* bsum = counts + M2;                     // <=1024
    unsigned* off1 = bsum + 1024;                     // N+1
    unsigned* off2 = off1 + N + 1;                    // N+1
    unsigned* cnt  = off2 + N + 1;                    // N
    float*    e    = (float*)(cnt + N);               // N
    float*    c    = e + N;                           // N
    float*    dinv = c + N;                           // N
    float*    part = dinv + N;                        // 3*NSTATB
    float*    st   = part + 3 * NSTATB;               // 3
    float*    S    = h0s;                             // reuse after k_agg

    const int nodeG = (N + 15) / 16;    // 16 nodes per 256-thread block
    const int nodeBlocks = (N + 255) / 256;

    // build both direction counts + one combined scan
    k_countboth<<<NC, 256, 0, stream>>>(src, dst, counts, NBUK, NC, E);
    k_scanA<<<NBs, 256, 0, stream>>>(counts, bsum, M2);
    k_scan2<<<1, 1024, 0, stream>>>(bsum, NBs);
    k_scanC<<<NBs, 256, 0, stream>>>(counts, bsum, M2);

    // direction 0: in-CSR (key=dst, payload=src) -> off1/pay1 + cnt/dinv
    k_bucket<<<NC, 256, 0, stream>>>(dst, src, counts, 0, 0u, bkt, NBUK, NC, E);
    k_csr<<<NBUK, 256, 0, stream>>>(bkt, counts, off1, pay1, cnt, dinv,
                                    0, 0u, NBUK, NC, N, E);
    // direction 1: out-CSR (key=src, payload=dst) -> off2/pay2
    k_bucket<<<NC, 256, 0, stream>>>(src, dst, counts, M, (unsigned)E, bkt, NBUK, NC, E);
    k_csr<<<NBUK, 256, 0, stream>>>(bkt, counts, off2, pay2, nullptr, nullptr,
                                    M, (unsigned)E, NBUK, NC, N, E);

    k_gemm<<<(N + GTN - 1) / GTN, 256, 0, stream>>>(x, W, dinv, h0s, N);
    k_agg<<<nodeG, 256, 0, stream>>>(off1, pay1, dinv, h0s, b, h, N);
    k_energy<<<nodeG, 256, 0, stream>>>(off1, pay1, h, e, S, N);
    k_stats1<<<NSTATB, 256, 0, stream>>>(e, Tptr, part, N);
    k_stats2<<<1, 256, 0, stream>>>(part, st, NSTATB);
    k_coef<<<nodeBlocks, 256, 0, stream>>>(e, Tptr, st, c, N);
    k_grad_final<<<nodeG, 256, 0, stream>>>(off2, pay2, c, h, S, cnt, wptr, out, N);
}